// Round 9
// baseline (130.935 us; speedup 1.0000x reference)
//
#include <hip/hip_runtime.h>
#include <math.h>

// (B,P,V,F,H) = (32,512,32,16,64). Round 9 = round 8 + VALU diet + L1 fix.
// Structure (verified r8): one bp per 2-wave block, wave u owns cols 32u..+31;
// weights pre-packed as bf16 MFMA B-frags in d_ws (36 KB), fetched per use on
// the VMEM pipe; wave-shared x-buffer, 3 __syncthreads/bp; LDS 4.7 KB/block.
// NEW: (1) v_cvt_pk_bf16_f32 packed converts (guarded; bfrne fallback);
// (2) mask hoisted to mz[8]/mn[8] once per wave: o = y*mz, pool-cand = y+mn
//     (replaces per-element bit-test + cndmask chains);
// (3) non-temporal X/M/OUT so streaming data stops thrashing the 36 KB WF
//     set out of the 32 KB L1 (WF re-fetch was ~590 MB of L2 traffic).
// MFMA 16x16x32 bf16: A[m=lane&15][k=quad*8+j], B[k=quad*8+j][n=lane&15],
//                     D[row=quad*4+reg][col=lane&15]  (verified rounds 2-8).
namespace {
constexpr int kXS = 72;
constexpr float kSlope = 0.01f;

typedef short bf16x8 __attribute__((ext_vector_type(8)));
typedef float f32x4  __attribute__((ext_vector_type(4)));
typedef float f32x4v __attribute__((ext_vector_type(4)));
typedef int   i32x4v __attribute__((ext_vector_type(4)));

__device__ __forceinline__ float lrelu(float x) { return fmaxf(x, kSlope * x); }

// fallback round-to-nearest-even f32->bf16 (finite inputs).
__device__ __forceinline__ unsigned short bfrne(float a) {
    union { float f; unsigned u; } v; v.f = a;
    return (unsigned short)((v.u + 0x7FFFu + ((v.u >> 16) & 1u)) >> 16);
}

// packed f32x2 -> bf16x2 (one v_cvt_pk_bf16_f32 on gfx950)
__device__ __forceinline__ short2 cvtpk(float a, float b) {
#if __has_builtin(__builtin_amdgcn_cvt_pk_bf16_f32)
    auto p = __builtin_amdgcn_cvt_pk_bf16_f32(a, b);
    short2 s; __builtin_memcpy(&s, &p, sizeof(s)); return s;
#else
    short2 s; s.x = (short)bfrne(a); s.y = (short)bfrne(b); return s;
#endif
}
__device__ __forceinline__ int cvtpk_i(float a, float b) {
    short2 s = cvtpk(a, b);
    int r; __builtin_memcpy(&r, &s, sizeof(r)); return r;
}

// ---- pre-pass: pack W1/W2/W3 as bf16 MFMA B-frags into d_ws ----
// frag f: 0..3 = W1 (nt=f, K=16 zero-padded); 4..19 = W2 (nt=(f-4)>>2,
// ks=(f-4)&3); 20..35 = W3. Lane l of frag f lives at ws[f*512 + l*8 ..+7].
__global__ void prep_weights(const float* __restrict__ W1,
                             const float* __restrict__ W2,
                             const float* __restrict__ W3,
                             unsigned short* __restrict__ ws)
{
    int t = blockIdx.x * blockDim.x + threadIdx.x;
    if (t >= 36 * 64) return;
    int f = t >> 6, l = t & 63, c = l & 15, q = l >> 4;
    unsigned short v[8] = {0, 0, 0, 0, 0, 0, 0, 0};
    const float* src = nullptr; int row = 0, k0 = 0, K = 0;
    if (f < 4) {
        if (q < 2) { src = W1; row = 16 * f + c; k0 = q * 8; K = 16; }
    } else if (f < 20) {
        int g = f - 4;  src = W2; row = 16 * (g >> 2) + c; k0 = (g & 3) * 32 + q * 8; K = 128;
    } else {
        int g = f - 20; src = W3; row = 16 * (g >> 2) + c; k0 = (g & 3) * 32 + q * 8; K = 128;
    }
    if (src) {
        #pragma unroll
        for (int j = 0; j < 8; ++j) v[j] = bfrne(src[row * K + k0 + j]);
    }
    unsigned short* dst = ws + (size_t)f * 512 + l * 8;
    *(ushort4*)(dst)     = make_ushort4(v[0], v[1], v[2], v[3]);
    *(ushort4*)(dst + 4) = make_ushort4(v[4], v[5], v[6], v[7]);
}

__global__ __launch_bounds__(128, 6) void fused_mlp_v9(
    const float* __restrict__ X, const int* __restrict__ M,
    const unsigned short* __restrict__ WF,
    const float* __restrict__ B1, const float* __restrict__ B2,
    const float* __restrict__ B3, float* __restrict__ OUT)
{
    __shared__ __align__(16) short xb[32 * kXS];  // 4608 B, shared by both waves
    __shared__ __align__(16) short pl[64];        //  128 B

    const int t = threadIdx.x, u = t >> 6, l = t & 63, c = l & 15, q = l >> 4;
    const size_t bp = (size_t)blockIdx.x;
    const int nb = 32 * u;                        // this wave's col base

    // ---- inputs for this bp (non-temporal: keep L1 for the WF frags) ----
    f32x4v xr[2][2];
    if (q < 2) {
        #pragma unroll
        for (int mt = 0; mt < 2; ++mt) {
            const f32x4v* p = (const f32x4v*)(X + (bp * 32 + 16 * mt + c) * 16 + q * 8);
            xr[mt][0] = __builtin_nontemporal_load(p);
            xr[mt][1] = __builtin_nontemporal_load(p + 1);
        }
    }
    const i32x4v* Mp = (const i32x4v*)(M + bp * 32);
    const i32x4v mr0 = __builtin_nontemporal_load(Mp + q);
    const i32x4v mr1 = __builtin_nontemporal_load(Mp + 4 + q);
    const unsigned mbits =
        (mr0[0] ? 1u : 0u)  | (mr0[1] ? 2u : 0u)  | (mr0[2] ? 4u : 0u)  | (mr0[3] ? 8u : 0u) |
        (mr1[0] ? 16u : 0u) | (mr1[1] ? 32u : 0u) | (mr1[2] ? 64u : 0u) | (mr1[3] ? 128u : 0u);
    const bool anyv = __any(mbits != 0);

    // hoisted per-row mask constants (index i = mt*4 + r)
    float mz[8], mn[8];
    #pragma unroll
    for (int i = 0; i < 8; ++i) {
        bool mk = (mbits >> i) & 1;
        mz[i] = mk ? 1.f : 0.f;
        mn[i] = mk ? 0.f : -INFINITY;
    }

    f32x4 acc[2][2];   // [mt][nt], nt local to this wave's 32-col half

    // ---- layer 1 (K=16 zero-padded to 32); W1 frags 2u+nt from WF ----
    {
        bf16x8 a1f[2];
        #pragma unroll
        for (int mt = 0; mt < 2; ++mt) {
            union { bf16x8 v; int i[4]; } uu;
            uu.v = bf16x8{};
            if (q < 2) {
                f32x4v f0 = xr[mt][0], f1 = xr[mt][1];
                uu.i[0] = cvtpk_i(f0[0], f0[1]);
                uu.i[1] = cvtpk_i(f0[2], f0[3]);
                uu.i[2] = cvtpk_i(f1[0], f1[1]);
                uu.i[3] = cvtpk_i(f1[2], f1[3]);
            }
            a1f[mt] = uu.v;
        }
        #pragma unroll
        for (int nt = 0; nt < 2; ++nt) {
            float b = B1[nb + 16 * nt + c];
            bf16x8 wf = *(const bf16x8*)(WF + (size_t)(2 * u + nt) * 512 + l * 8);
            f32x4 c0 = { b, b, b, b };
            acc[0][nt] = __builtin_amdgcn_mfma_f32_16x16x32_bf16(a1f[0], wf, c0, 0, 0, 0);
            acc[1][nt] = __builtin_amdgcn_mfma_f32_16x16x32_bf16(a1f[1], wf, c0, 0, 0, 0);
        }
    }

    // ---- epilogue: lrelu, o = y*mz, pool-cand = y+mn, packed cvt writes ----
    auto epilogue = [&]() {
        float pool[2];
        #pragma unroll
        for (int nt = 0; nt < 2; ++nt) {
            float pv = -INFINITY;
            #pragma unroll
            for (int mt = 0; mt < 2; ++mt) {
                short* base = &xb[(16 * mt + 4 * q) * kXS + nb + 16 * nt + c];
                float o[4];
                #pragma unroll
                for (int r = 0; r < 4; ++r) {
                    float y = lrelu(acc[mt][nt][r]);
                    o[r] = y * mz[mt * 4 + r];          // masked-out -> 0
                    pv = fmaxf(pv, y + mn[mt * 4 + r]); // masked-out -> -inf
                }
                short2 s01 = cvtpk(o[0], o[1]);
                short2 s23 = cvtpk(o[2], o[3]);
                base[0 * kXS] = s01.x; base[1 * kXS] = s01.y;
                base[2 * kXS] = s23.x; base[3 * kXS] = s23.y;
            }
            pv = fmaxf(pv, __shfl_xor(pv, 16));
            pv = fmaxf(pv, __shfl_xor(pv, 32));
            pool[nt] = anyv ? pv : 0.f;
        }
        if (q < 2) pl[nb + 16 * q + c] = (short)bfrne(q ? pool[1] : pool[0]);
    };

    // ---- K=128 layer: A-frags span BOTH col halves (shared xb/pl) ----
    auto layerK = [&](int fb, const float* __restrict__ Bv) {
        bf16x8 a00 = *(const bf16x8*)&xb[(     c) * kXS      + q * 8];
        bf16x8 a01 = *(const bf16x8*)&xb[(16 + c) * kXS      + q * 8];
        bf16x8 a10 = *(const bf16x8*)&xb[(     c) * kXS + 32 + q * 8];
        bf16x8 a11 = *(const bf16x8*)&xb[(16 + c) * kXS + 32 + q * 8];
        bf16x8 ap0 = *(const bf16x8*)&pl[q * 8];        // quad-broadcast
        bf16x8 ap1 = *(const bf16x8*)&pl[32 + q * 8];
        #pragma unroll
        for (int nt = 0; nt < 2; ++nt) {
            float b = Bv[nb + 16 * nt + c];
            acc[0][nt] = f32x4{ b, b, b, b };
            acc[1][nt] = acc[0][nt];
        }
        #pragma unroll
        for (int ks = 0; ks < 4; ++ks) {
            bf16x8 am0 = (ks == 0) ? a00 : (ks == 1) ? a10 : (ks == 2) ? ap0 : ap1;
            bf16x8 am1 = (ks == 0) ? a01 : (ks == 1) ? a11 : (ks == 2) ? ap0 : ap1;
            #pragma unroll
            for (int nt = 0; nt < 2; ++nt) {
                int f = fb + (2 * u + nt) * 4 + ks;
                bf16x8 wf = *(const bf16x8*)(WF + (size_t)f * 512 + l * 8);
                acc[0][nt] = __builtin_amdgcn_mfma_f32_16x16x32_bf16(am0, wf, acc[0][nt], 0, 0, 0);
                acc[1][nt] = __builtin_amdgcn_mfma_f32_16x16x32_bf16(am1, wf, acc[1][nt], 0, 0, 0);
            }
        }
    };

    epilogue();            // x2 = [out1 | pool1]
    __syncthreads();       // writes visible to partner wave
    layerK(4, B2);         // layer 2
    __syncthreads();       // partner's reads done before overwrite (WAR)
    epilogue();            // x3 in place
    __syncthreads();       // writes visible
    layerK(20, B3);        // layer 3

    // ---- layer-3 pool == final output ----
    #pragma unroll
    for (int nt = 0; nt < 2; ++nt) {
        float pv = -INFINITY;
        #pragma unroll
        for (int mt = 0; mt < 2; ++mt)
            #pragma unroll
            for (int r = 0; r < 4; ++r) {
                float y = lrelu(acc[mt][nt][r]);
                pv = fmaxf(pv, y + mn[mt * 4 + r]);
            }
        pv = fmaxf(pv, __shfl_xor(pv, 16));
        pv = fmaxf(pv, __shfl_xor(pv, 32));
        pv = anyv ? pv : 0.f;
        if (q == 0) __builtin_nontemporal_store(pv, &OUT[bp * 64 + nb + 16 * nt + c]);
    }
}
} // namespace

extern "C" void kernel_launch(void* const* d_in, const int* in_sizes, int n_in,
                              void* d_out, int out_size, void* d_ws, size_t ws_size,
                              hipStream_t stream) {
    (void)in_sizes; (void)n_in; (void)ws_size; (void)out_size;
    const float* X  = (const float*)d_in[0];
    const int*   M  = (const int*)d_in[1];
    const float* W1 = (const float*)d_in[2];
    const float* B1 = (const float*)d_in[3];
    const float* W2 = (const float*)d_in[4];
    const float* B2 = (const float*)d_in[5];
    const float* W3 = (const float*)d_in[6];
    const float* B3 = (const float*)d_in[7];
    float* OUT = (float*)d_out;
    unsigned short* WF = (unsigned short*)d_ws;   // needs 36 KB of scratch

    prep_weights<<<(36 * 64 + 255) / 256, 256, 0, stream>>>(W1, W2, W3, WF);
    // 16384 blocks x 2 waves; one bp per block, each wave owns 32 output cols
    fused_mlp_v9<<<16384, 128, 0, stream>>>(X, M, WF, B1, B2, B3, OUT);
}